// Round 1
// baseline (160.925 us; speedup 1.0000x reference)
//
#include <hip/hip_runtime.h>
#include <math.h>

// Problem constants
#define BB 16
#define CC 512
#define LL 8192
#define HH 32          // CC / 16
#define BC (BB * CC)   // 8192 rows

// ---------------------------------------------------------------------------
// Kernel 1: per-(b,c) mean over L.  One block per row, 256 threads,
// each thread reads 8 float4 (32 elems), coalesced.
// ---------------------------------------------------------------------------
__global__ __launch_bounds__(256) void k_mean(const float* __restrict__ x,
                                              float* __restrict__ s) {
    const int row = blockIdx.x;                       // 0..BC-1
    const int tid = threadIdx.x;
    const float4* xr = (const float4*)(x + (size_t)row * LL);

    float acc = 0.0f;
#pragma unroll
    for (int i = 0; i < LL / 4 / 256; ++i) {          // 8 iterations
        float4 v = xr[i * 256 + tid];
        acc += (v.x + v.y) + (v.z + v.w);
    }
    // wave64 reduce
#pragma unroll
    for (int off = 32; off > 0; off >>= 1)
        acc += __shfl_down(acc, off, 64);

    __shared__ float part[4];
    const int lane = tid & 63, wv = tid >> 6;
    if (lane == 0) part[wv] = acc;
    __syncthreads();
    if (tid == 0) {
        float t = (part[0] + part[1]) + (part[2] + part[3]);
        s[row] = t * (1.0f / (float)LL);
    }
}

// ---------------------------------------------------------------------------
// Kernel 2: tiny FC -> relu -> FC -> sigmoid.  One block per batch b,
// 512 threads.  s[b,:] staged in LDS; h computed by 32 groups of 16
// threads; then all 512 threads produce one gate each.
// ---------------------------------------------------------------------------
__global__ __launch_bounds__(512) void k_gates(const float* __restrict__ s,
                                               const float* __restrict__ w1,
                                               const float* __restrict__ b1,
                                               const float* __restrict__ w2,
                                               const float* __restrict__ b2,
                                               float* __restrict__ g) {
    const int b   = blockIdx.x;       // 0..15
    const int tid = threadIdx.x;      // 0..511

    __shared__ float sh[CC];
    __shared__ float partial[HH][17]; // +1 pad
    __shared__ float h[HH];

    sh[tid] = s[b * CC + tid];
    __syncthreads();

    // h[j] = relu(b1[j] + sum_c sh[c] * w1[j*CC + c])
    {
        const int j   = tid >> 4;     // 0..31
        const int seg = tid & 15;     // 0..15, each covers 32 c's
        const float* wrow = w1 + (size_t)j * CC + seg * 32;
        const float* srow = sh + seg * 32;
        float p = 0.0f;
#pragma unroll
        for (int c = 0; c < 32; ++c) p += srow[c] * wrow[c];
        partial[j][seg] = p;
    }
    __syncthreads();
    if (tid < HH) {
        float t = b1[tid];
#pragma unroll
        for (int k = 0; k < 16; ++k) t += partial[tid][k];
        h[tid] = t > 0.0f ? t : 0.0f;
    }
    __syncthreads();

    // g[b*CC + c] = sigmoid(b2[c] + sum_j h[j] * w2[c*HH + j])
    {
        const int c = tid;
        const float* wrow = w2 + (size_t)c * HH;
        float z = b2[c];
#pragma unroll
        for (int j = 0; j < HH; ++j) z += h[j] * wrow[j];
        g[b * CC + c] = 1.0f / (1.0f + expf(-z));
    }
}

// ---------------------------------------------------------------------------
// Kernel 3: out = x * g[row], broadcast per row.  One block per row,
// 256 threads, 8 float4 per thread.
// ---------------------------------------------------------------------------
__global__ __launch_bounds__(256) void k_scale(const float* __restrict__ x,
                                               const float* __restrict__ g,
                                               float* __restrict__ out) {
    const int row  = blockIdx.x;      // 0..BC-1
    const int tid  = threadIdx.x;
    const float gate = g[row];

    const float4* xr = (const float4*)(x   + (size_t)row * LL);
    float4*       orr = (float4*)(out + (size_t)row * LL);
#pragma unroll
    for (int i = 0; i < LL / 4 / 256; ++i) {          // 8 iterations
        float4 v = xr[i * 256 + tid];
        v.x *= gate; v.y *= gate; v.z *= gate; v.w *= gate;
        orr[i * 256 + tid] = v;
    }
}

extern "C" void kernel_launch(void* const* d_in, const int* in_sizes, int n_in,
                              void* d_out, int out_size, void* d_ws, size_t ws_size,
                              hipStream_t stream) {
    const float* x  = (const float*)d_in[0];
    const float* w1 = (const float*)d_in[1];
    const float* b1 = (const float*)d_in[2];
    const float* w2 = (const float*)d_in[3];
    const float* b2 = (const float*)d_in[4];
    float* out = (float*)d_out;

    float* s = (float*)d_ws;          // BC floats
    float* g = s + BC;                // BC floats

    k_mean <<<BC, 256, 0, stream>>>(x, s);
    k_gates<<<BB, 512, 0, stream>>>(s, w1, b1, w2, b2, g);
    k_scale<<<BC, 256, 0, stream>>>(x, g, out);
}

// Round 3
// 127.535 us; speedup vs baseline: 1.2618x; 1.2618x over previous
//
#include <hip/hip_runtime.h>
#include <math.h>

// Problem constants
#define BB 16
#define CC 512
#define LL 8192
#define HH 32          // CC / 16
#define BC (BB * CC)   // 8192 rows

typedef float fv4 __attribute__((ext_vector_type(4)));

// ---------------------------------------------------------------------------
// Kernel 1: per-(b,c) mean over L.  One block per row, 256 threads,
// each thread reads 8 float4 (32 elems), coalesced.  Regular (caching)
// loads on purpose: we WANT x resident in L3 for the scale pass.
// ---------------------------------------------------------------------------
__global__ __launch_bounds__(256) void k_mean(const float* __restrict__ x,
                                              float* __restrict__ s) {
    const int row = blockIdx.x;                       // 0..BC-1
    const int tid = threadIdx.x;
    const fv4* xr = (const fv4*)(x + (size_t)row * LL);

    float acc = 0.0f;
#pragma unroll
    for (int i = 0; i < LL / 4 / 256; ++i) {          // 8 iterations
        fv4 v = xr[i * 256 + tid];
        acc += (v.x + v.y) + (v.z + v.w);
    }
    // wave64 reduce
#pragma unroll
    for (int off = 32; off > 0; off >>= 1)
        acc += __shfl_down(acc, off, 64);

    __shared__ float part[4];
    const int lane = tid & 63, wv = tid >> 6;
    if (lane == 0) part[wv] = acc;
    __syncthreads();
    if (tid == 0) {
        float t = (part[0] + part[1]) + (part[2] + part[3]);
        s[row] = t * (1.0f / (float)LL);
    }
}

// ---------------------------------------------------------------------------
// Kernel 2 (fused gates + scale): 2048 blocks, each handles 4 channels of
// one batch.  Each block redundantly computes h = relu(s[b]@w1^T + b1)
// (16K FMA, w1 is 64KB L2-resident — free), then its 4 gates, then scales
// 4 rows of x with NON-TEMPORAL stores so the output stream does not evict
// x from L3.  Block order is REVERSED so the first-dispatched blocks read
// the rows k_mean touched last (most recent in L3).
// ---------------------------------------------------------------------------
__global__ __launch_bounds__(256) void k_scale_fused(
        const float* __restrict__ x,  const float* __restrict__ s,
        const float* __restrict__ w1, const float* __restrict__ b1,
        const float* __restrict__ w2, const float* __restrict__ b2,
        float* __restrict__ out) {
    const int bid   = (int)gridDim.x - 1 - (int)blockIdx.x;  // reversed
    const int b     = bid >> 7;        // 0..15   (128 blocks per batch)
    const int chunk = bid & 127;       // 0..127  (4 channels each)
    const int tid   = threadIdx.x;

    __shared__ float partial[HH][9];   // +1 pad
    __shared__ float h[HH];
    __shared__ float g4[4];

    // h[j] = relu(b1[j] + sum_c s[b,c] * w1[j,c])
    {
        const int j   = tid >> 3;      // 0..31
        const int seg = tid & 7;       // 0..7, 64 c's each
        const float* srow = s  + b * CC + seg * 64;
        const float* wrow = w1 + (size_t)j * CC + seg * 64;
        float p = 0.0f;
#pragma unroll
        for (int c = 0; c < 64; ++c) p += srow[c] * wrow[c];
        partial[j][seg] = p;
    }
    __syncthreads();
    if (tid < HH) {
        float t = b1[tid];
#pragma unroll
        for (int k = 0; k < 8; ++k) t += partial[tid][k];
        h[tid] = t > 0.0f ? t : 0.0f;
    }
    __syncthreads();
    if (tid < 4) {
        const int c = chunk * 4 + tid;
        const float* wrow = w2 + (size_t)c * HH;
        float z = b2[c];
#pragma unroll
        for (int j = 0; j < HH; ++j) z += h[j] * wrow[j];
        g4[tid] = 1.0f / (1.0f + expf(-z));
    }
    __syncthreads();

    // scale 4 rows, nt-stores for out
#pragma unroll
    for (int r = 0; r < 4; ++r) {
        const int c = chunk * 4 + r;
        const size_t off = ((size_t)b * CC + c) * (size_t)LL;
        const fv4* xr  = (const fv4*)(x + off);
        fv4*       orr = (fv4*)(out + off);
        const float gate = g4[r];
#pragma unroll
        for (int i = 0; i < LL / 4 / 256; ++i) {
            fv4 v = xr[i * 256 + tid];
            v *= gate;
            __builtin_nontemporal_store(v, &orr[i * 256 + tid]);
        }
    }
}

extern "C" void kernel_launch(void* const* d_in, const int* in_sizes, int n_in,
                              void* d_out, int out_size, void* d_ws, size_t ws_size,
                              hipStream_t stream) {
    const float* x  = (const float*)d_in[0];
    const float* w1 = (const float*)d_in[1];
    const float* b1 = (const float*)d_in[2];
    const float* w2 = (const float*)d_in[3];
    const float* b2 = (const float*)d_in[4];
    float* out = (float*)d_out;

    float* s = (float*)d_ws;          // BC floats

    k_mean       <<<BC,   256, 0, stream>>>(x, s);
    k_scale_fused<<<BC/4, 256, 0, stream>>>(x, s, w1, b1, w2, b2, out);
}